// Round 5
// baseline (335.551 us; speedup 1.0000x reference)
//
#include <hip/hip_runtime.h>
#include <hip/hip_bf16.h>

typedef unsigned short u16;
typedef __bf16 bf16x8 __attribute__((ext_vector_type(8)));
typedef __bf16 bf16x4 __attribute__((ext_vector_type(4)));
typedef u16 u16x8 __attribute__((ext_vector_type(8)));
typedef float f32x4 __attribute__((ext_vector_type(4)));
typedef float f32x16 __attribute__((ext_vector_type(16)));

__device__ __forceinline__ u16 f2bf(float f) {
    unsigned u = __float_as_uint(f);
    return (u16)((u + 0x7fffu + ((u >> 16) & 1u)) >> 16);
}
__device__ __forceinline__ unsigned pkbf2(float a, float b) {
    __hip_bfloat162 h = __float22bfloat162_rn(make_float2(a, b));
    return *(unsigned*)&h;
}

// ---------------- fp32 -> bf16 convert ----------------
__global__ void cvt_bf16(const float* __restrict__ src, u16* __restrict__ dst, int n4) {
    int i = blockIdx.x * 256 + threadIdx.x;
    if (i >= n4) return;
    float4 v = *(const float4*)(src + (size_t)i * 4);
    uint2 o; o.x = pkbf2(v.x, v.y); o.y = pkbf2(v.z, v.w);
    *(uint2*)(dst + (size_t)i * 4) = o;
}

// ---------------- GEMM core: 256x128 tile, BK=32, stride-40 LDS, dbuf, ------
// single barrier per K-iter. Wave w owns rows (w>>1)*128..+127, cols (w&1)*64..+63.
#define LSTR 40
__device__ __forceinline__ void gemm_core256(const u16* __restrict__ Ab,
                                             const u16* __restrict__ Bb, int K,
                                             f32x4 acc[8][4], int tid) {
    __shared__ u16 As[2][256 * LSTR];
    __shared__ u16 Bs[2][128 * LSTR];
    const int wave = tid >> 6, lane = tid & 63;
    const int quad = lane >> 4, l16 = lane & 15;
    const int wr = (wave >> 1) * 128, wc = (wave & 1) * 64;
    const int strow = tid >> 2;          // 0..63
    const int stk = (tid & 3) * 8;       // k-offset elems

    const u16* pa[4]; int la[4];
#pragma unroll
    for (int p = 0; p < 4; ++p) {
        int row = p * 64 + strow;
        pa[p] = Ab + (size_t)row * K + stk;
        la[p] = row * LSTR + stk;
    }
    const u16* pb[2]; int lb[2];
#pragma unroll
    for (int p = 0; p < 2; ++p) {
        int row = p * 64 + strow;
        pb[p] = Bb + (size_t)row * K + stk;
        lb[p] = row * LSTR + stk;
    }

    // prologue: tile 0
    u16x8 ar[4], br[2];
#pragma unroll
    for (int p = 0; p < 4; ++p) ar[p] = *(const u16x8*)pa[p];
#pragma unroll
    for (int p = 0; p < 2; ++p) br[p] = *(const u16x8*)pb[p];
#pragma unroll
    for (int p = 0; p < 4; ++p) *(u16x8*)&As[0][la[p]] = ar[p];
#pragma unroll
    for (int p = 0; p < 2; ++p) *(u16x8*)&Bs[0][lb[p]] = br[p];
    __syncthreads();

    const int nk = K >> 5;
    for (int kt = 0; kt < nk; ++kt) {
        const int cur = kt & 1, nxt = cur ^ 1;
        if (kt + 1 < nk) {
            const int off = (kt + 1) * 32;
#pragma unroll
            for (int p = 0; p < 4; ++p) ar[p] = *(const u16x8*)(pa[p] + off);
#pragma unroll
            for (int p = 0; p < 2; ++p) br[p] = *(const u16x8*)(pb[p] + off);
        }
        bf16x8 af[8], bfr[4];
#pragma unroll
        for (int mt = 0; mt < 8; ++mt)
            af[mt] = *(const bf16x8*)&As[cur][(wr + mt * 16 + l16) * LSTR + quad * 8];
#pragma unroll
        for (int nt = 0; nt < 4; ++nt)
            bfr[nt] = *(const bf16x8*)&Bs[cur][(wc + nt * 16 + l16) * LSTR + quad * 8];
#pragma unroll
        for (int mt = 0; mt < 8; ++mt)
#pragma unroll
            for (int nt = 0; nt < 4; ++nt)
                acc[mt][nt] = __builtin_amdgcn_mfma_f32_16x16x32_bf16(
                    af[mt], bfr[nt], acc[mt][nt], 0, 0, 0);
        if (kt + 1 < nk) {
#pragma unroll
            for (int p = 0; p < 4; ++p) *(u16x8*)&As[nxt][la[p]] = ar[p];
#pragma unroll
            for (int p = 0; p < 2; ++p) *(u16x8*)&Bs[nxt][lb[p]] = br[p];
        }
        __syncthreads();
    }
}

// ---------------- plain GEMM (o-proj): C = A * B^T, fp32 out ----------------
__global__ __launch_bounds__(256, 2)
void gemm_bt(const u16* __restrict__ A, const u16* __restrict__ B,
             float* __restrict__ C, int M, int N, int K) {
    const int tid = threadIdx.x, wave = tid >> 6, lane = tid & 63;
    const int quad = lane >> 4, l16 = lane & 15;
    const int wr = (wave >> 1) * 128, wc = (wave & 1) * 64;
    const size_t bm = (size_t)blockIdx.y * 256, bn = (size_t)blockIdx.x * 128;
    f32x4 acc[8][4] = {};
    gemm_core256(A + bm * K, B + bn * K, K, acc, tid);
#pragma unroll
    for (int mt = 0; mt < 8; ++mt)
#pragma unroll
        for (int nt = 0; nt < 4; ++nt)
#pragma unroll
            for (int r = 0; r < 4; ++r)
                C[(bm + wr + mt * 16 + quad * 4 + r) * (size_t)N + bn + wc + nt * 16 + l16] =
                    acc[mt][nt][r];
}

// ---------------- fused QKV GEMM: RMSNorm+RoPE (q,k) / transpose (v) --------
// N-tile tn: 0..15 = q head, 16..19 = k head, 20..23 = v head. 128 cols = head dim.
__global__ __launch_bounds__(256, 2)
void gemm_qkv(const u16* __restrict__ xb, const u16* __restrict__ wq,
              const float* __restrict__ qw, const float* __restrict__ kw,
              const float* __restrict__ fcos, const float* __restrict__ fsin,
              u16* __restrict__ qb, u16* __restrict__ kb, u16* __restrict__ vt) {
    const int tid = threadIdx.x, wave = tid >> 6, lane = tid & 63;
    const int quad = lane >> 4, l16 = lane & 15;
    const int wr = (wave >> 1) * 128, wc = (wave & 1) * 64;
    const int tn = blockIdx.x, bmb = blockIdx.y;
    f32x4 acc[8][4] = {};
    gemm_core256(xb + (size_t)bmb * 256 * 2048, wq + (size_t)tn * 128 * 2048, 2048,
                 acc, tid);

    const int b = bmb >> 3;
    const int sbase = (bmb & 7) * 256 + wr;   // + mt*16 + quad*4 + r

    if (tn >= 20) {
        // V: bf16 + transpose store, 4 consecutive s per bf16x4
        const int kv = tn - 20;
        u16* base = vt + (size_t)(b * 4 + kv) * 128 * 2048;
#pragma unroll
        for (int mt = 0; mt < 8; ++mt) {
            int s0 = sbase + mt * 16 + quad * 4;
#pragma unroll
            for (int nt = 0; nt < 4; ++nt) {
                int col = wc + nt * 16 + l16;
                bf16x4 pv;
#pragma unroll
                for (int r = 0; r < 4; ++r) pv[r] = (__bf16)acc[mt][nt][r];
                *(bf16x4*)(base + (size_t)col * 2048 + s0) = pv;
            }
        }
        return;
    }

    // Q/K: RMSNorm + RoPE
    __shared__ float red[2][256];
    float ssq;
#pragma unroll
    for (int mt = 0; mt < 8; ++mt)
#pragma unroll
        for (int r = 0; r < 4; ++r) {
            float t = 0.f;
#pragma unroll
            for (int nt = 0; nt < 4; ++nt) t += acc[mt][nt][r] * acc[mt][nt][r];
#pragma unroll
            for (int off = 1; off <= 8; off <<= 1) t += __shfl_xor(t, off);
            if (l16 == 0) red[wave & 1][wr + mt * 16 + quad * 4 + r] = t;
        }
    __syncthreads();

    const float qscl = (tn < 16) ? 0.08838834764831845f * 1.4426950408889634f : 1.0f;
    const float* wp = (tn < 16) ? qw : kw;
    float wcol[4];
#pragma unroll
    for (int nt = 0; nt < 4; ++nt) wcol[nt] = wp[wc + nt * 16 + l16];
    u16* dstbase = (tn < 16) ? qb + (size_t)(b * 16 + tn) * 2048 * 128
                             : kb + (size_t)(b * 4 + (tn - 16)) * 2048 * 128;
    const float sgn = (l16 & 1) ? 1.f : -1.f;

#pragma unroll
    for (int mt = 0; mt < 8; ++mt) {
#pragma unroll
        for (int r = 0; r < 4; ++r) {
            int row = wr + mt * 16 + quad * 4 + r;
            float var = (red[0][row] + red[1][row]) * (1.0f / 128.0f);
            float rms = rsqrtf(var + 1.1920928955078125e-07f) * qscl;
            int s = sbase + mt * 16 + quad * 4 + r;
            const float* fc = fcos + (size_t)s * 128 + wc;
            const float* fn = fsin + (size_t)s * 128 + wc;
            u16* drow = dstbase + (size_t)s * 128 + wc;
#pragma unroll
            for (int nt = 0; nt < 4; ++nt) {
                float y = acc[mt][nt][r] * rms * wcol[nt];
                float yp = __shfl_xor(y, 1);
                float o = y * fc[nt * 16 + l16] + sgn * yp * fn[nt * 16 + l16];
                drow[nt * 16 + l16] = f2bf(o);
            }
        }
    }
}

// ---------------- flash attention v3: 32x32 mfma, reg-P, dbuf, swizzled LDS --
#define KBUF(c) ((c) * 8192)
#define VBUF(c) (16384 + (c) * 8192)
__global__ __launch_bounds__(256, 2)
void flash_attn(const u16* __restrict__ qb, const u16* __restrict__ kb,
                const u16* __restrict__ vt, u16* __restrict__ ab) {
    __shared__ u16 smem[32768];
    __shared__ float Llds[128];

    const int tid = threadIdx.x;
    const int wave = tid >> 6, lane = tid & 63;
    const int hf = lane >> 5, c32 = lane & 31;
    const int qt = blockIdx.x, hh = blockIdx.y, bb = blockIdx.z;
    const int kh = hh >> 2;

    const u16* Qbase = qb + (size_t)(bb * 16 + hh) * 2048 * 128;
    const u16* Kbase = kb + (size_t)(bb * 4 + kh) * 2048 * 128;
    const u16* Vbase = vt + (size_t)(bb * 4 + kh) * 128 * 2048;

    bf16x8 aq[8];
#pragma unroll
    for (int kq = 0; kq < 8; ++kq)
        aq[kq] = *(const bf16x8*)(Qbase +
            (size_t)(qt * 128 + wave * 32 + c32) * 128 + kq * 16 + hf * 8);

    f32x16 O[4] = {};
    float lacc = 0.f;

    const int st_key = tid >> 4, st_c16 = tid & 15;
    const int st_d = tid >> 3, st_c8 = tid & 7;

    u16x8 kreg[4], vreg[4];
#pragma unroll
    for (int it = 0; it < 4; ++it) {
        int key = st_key + it * 16, d = st_d + it * 32;
        kreg[it] = *(const u16x8*)(Kbase + (size_t)key * 128 + st_c16 * 8);
        vreg[it] = *(const u16x8*)(Vbase + (size_t)d * 2048 + st_c8 * 8);
    }
#pragma unroll
    for (int it = 0; it < 4; ++it) {
        int key = st_key + it * 16, d = st_d + it * 32;
        *(u16x8*)&smem[KBUF(0) + key * 128 + ((st_c16 ^ (key & 7)) * 8)] = kreg[it];
        *(u16x8*)&smem[VBUF(0) + d * 64 + ((st_c8 ^ (d & 7)) * 8)] = vreg[it];
    }
    __syncthreads();

    for (int kt = 0; kt < 32; ++kt) {
        const int cur = kt & 1, nxt = cur ^ 1;
        if (kt < 31) {
            const int key0n = (kt + 1) * 64;
#pragma unroll
            for (int it = 0; it < 4; ++it) {
                int key = st_key + it * 16, d = st_d + it * 32;
                kreg[it] = *(const u16x8*)(Kbase + (size_t)(key0n + key) * 128 + st_c16 * 8);
                vreg[it] = *(const u16x8*)(Vbase + (size_t)d * 2048 + key0n + st_c8 * 8);
            }
        }

        f32x16 sc[2] = {};
#pragma unroll
        for (int kq = 0; kq < 8; ++kq) {
#pragma unroll
            for (int mt = 0; mt < 2; ++mt) {
                bf16x8 kf = *(const bf16x8*)&smem[KBUF(cur) + (mt * 32 + c32) * 128 +
                                                 (((kq * 2 + hf) ^ (c32 & 7)) * 8)];
                sc[mt] = __builtin_amdgcn_mfma_f32_32x32x16_bf16(kf, aq[kq], sc[mt], 0, 0, 0);
            }
        }

        int pdw[2][8];
#pragma unroll
        for (int mt = 0; mt < 2; ++mt) {
            float p[16];
#pragma unroll
            for (int r = 0; r < 16; ++r) {
                p[r] = __builtin_amdgcn_exp2f(sc[mt][r]);
                lacc += p[r];
            }
#pragma unroll
            for (int i = 0; i < 8; ++i) pdw[mt][i] = (int)pkbf2(p[2 * i], p[2 * i + 1]);
        }

        if (kt < 31) {
#pragma unroll
            for (int it = 0; it < 4; ++it) {
                int key = st_key + it * 16, d = st_d + it * 32;
                *(u16x8*)&smem[KBUF(nxt) + key * 128 + ((st_c16 ^ (key & 7)) * 8)] = kreg[it];
                *(u16x8*)&smem[VBUF(nxt) + d * 64 + ((st_c8 ^ (d & 7)) * 8)] = vreg[it];
            }
        }

#pragma unroll
        for (int kc = 0; kc < 4; ++kc) {
            const int mt = kc >> 1, L = kc & 1;
            int s0 = hf ? pdw[mt][4 * L + 0] : pdw[mt][4 * L + 2];
            int s1 = hf ? pdw[mt][4 * L + 1] : pdw[mt][4 * L + 3];
            int r0 = __shfl_xor(s0, 32);
            int r1 = __shfl_xor(s1, 32);
            union { int i[4]; bf16x8 v; } u;
            u.i[0] = hf ? r0 : pdw[mt][4 * L + 0];
            u.i[1] = hf ? r1 : pdw[mt][4 * L + 1];
            u.i[2] = hf ? pdw[mt][4 * L + 2] : r0;
            u.i[3] = hf ? pdw[mt][4 * L + 3] : r1;
#pragma unroll
            for (int dt = 0; dt < 4; ++dt) {
                bf16x8 vf = *(const bf16x8*)&smem[VBUF(cur) + (dt * 32 + c32) * 64 +
                                                 (((kc * 2 + hf) ^ (c32 & 7)) * 8)];
                O[dt] = __builtin_amdgcn_mfma_f32_32x32x16_bf16(u.v, vf, O[dt], 0, 0, 0);
            }
        }
        __syncthreads();
    }

    float l = lacc + __shfl_xor(lacc, 32);
    if (hf == 0) Llds[wave * 32 + c32] = l;

    float inv[16];
#pragma unroll
    for (int r = 0; r < 16; ++r)
        inv[r] = __builtin_amdgcn_rcpf(Llds[wave * 32 + (r & 3) + 8 * (r >> 2) + 4 * hf]);

    u16* scr = &smem[wave * 32 * 136];
#pragma unroll
    for (int dt = 0; dt < 4; ++dt)
#pragma unroll
        for (int r = 0; r < 16; ++r) {
            int q_r = (r & 3) + 8 * (r >> 2) + 4 * hf;
            scr[q_r * 136 + dt * 32 + c32] = f2bf(O[dt][r] * inv[r]);
        }
#pragma unroll
    for (int it = 0; it < 8; ++it) {
        int f = it * 64 + lane;
        int row = f >> 4, c = f & 15;
        u16x8 v = *(const u16x8*)&scr[row * 136 + c * 8];
        int qg = qt * 128 + wave * 32 + row;
        *(u16x8*)(ab + ((size_t)(bb * 2048 + qg)) * 2048 + hh * 128 + c * 8) = v;
    }
}

// ---------------- host launch ----------------
extern "C" void kernel_launch(void* const* d_in, const int* in_sizes, int n_in,
                              void* d_out, int out_size, void* d_ws, size_t ws_size,
                              hipStream_t stream) {
    const float* x    = (const float*)d_in[0];
    const float* wqkv = (const float*)d_in[1];
    const float* wo   = (const float*)d_in[2];
    const float* qw   = (const float*)d_in[3];
    const float* kw   = (const float*)d_in[4];
    const float* fc   = (const float*)d_in[5];
    const float* fs   = (const float*)d_in[6];
    float* out = (float*)d_out;
    char* ws = (char*)d_ws;

    u16* xb    = (u16*)(ws + 0);          // 4096x2048 bf16 (16 MB)
    u16* wqkvb = (u16*)(ws + 16777216);   // 3072x2048 bf16 (12 MB)
    u16* wob   = (u16*)(ws + 29360128);   // 2048x2048 bf16 ( 8 MB)
    u16* qb    = (u16*)(ws + 37748736);   // [2,16,2048,128] (16 MB)
    u16* kb    = (u16*)(ws + 54525952);   // [2,4,2048,128]  ( 4 MB)
    u16* vt    = (u16*)(ws + 58720256);   // [2,4,128,2048]  ( 4 MB)
    u16* ab    = (u16*)(ws + 62914560);   // 4096x2048 bf16  (16 MB)

    cvt_bf16<<<8192, 256, 0, stream>>>(x, xb, 2097152);
    cvt_bf16<<<6144, 256, 0, stream>>>(wqkv, wqkvb, 1572864);
    cvt_bf16<<<4096, 256, 0, stream>>>(wo, wob, 1048576);
    gemm_qkv<<<dim3(24, 16), 256, 0, stream>>>(xb, wqkvb, qw, kw, fc, fs, qb, kb, vt);
    flash_attn<<<dim3(16, 16, 2), 256, 0, stream>>>(qb, kb, vt, ab);
    gemm_bt<<<dim3(16, 16), 256, 0, stream>>>(ab, wob, out, 4096, 2048, 2048);
}